// Round 4
// baseline (474.097 us; speedup 1.0000x reference)
//
#include <hip/hip_runtime.h>
#include <stdint.h>
#include <math.h>

// ReformerAttention on MI355X — all fp32 I/O (per reference dtypes).
// B=2, T=2048, E=512, H=8, Dh=64, 2 hash rounds, buckets<32 attend.
// Projection row p (of the [T*B,E]-flattened swapaxes result) = logical
// (b'=p/T, t'=p%T); it gathers input row (b=p%2, t=p/2).

#define T_ 2048
#define E_ 512
#define H_ 8
#define DH_ 64
#define B_ 2
#define M_ 4096        // B_*T_
#define NROUND 2
#define NBUCKET 32

// ---------------------------------------------------------------------------
// QKV projection: C[p,n] = sum_k X[gather(p),k]*W[n,k] + bias[n]
// ---------------------------------------------------------------------------
__global__ __launch_bounds__(256) void qkv_gemm(
    const float* __restrict__ Xq, const float* __restrict__ Xk,
    const float* __restrict__ Xv,
    const float* __restrict__ Wq, const float* __restrict__ bq,
    const float* __restrict__ Wk, const float* __restrict__ bk,
    const float* __restrict__ Wv, const float* __restrict__ bv,
    float* __restrict__ Qo, float* __restrict__ Ko, float* __restrict__ Vo)
{
  const float* X; const float* W; const float* bias; float* C;
  if (blockIdx.z == 0)      { X = Xq; W = Wq; bias = bq; C = Qo; }
  else if (blockIdx.z == 1) { X = Xk; W = Wk; bias = bk; C = Ko; }
  else                      { X = Xv; W = Wv; bias = bv; C = Vo; }

  __shared__ __align__(16) float As[16 * 68];  // [k][m], stride 68 breaks pow2
  __shared__ __align__(16) float Bs[16 * 68];  // [k][n]

  const int tid = threadIdx.x;
  const int tx = tid & 15, ty = tid >> 4;
  const int m0 = blockIdx.y * 64, n0 = blockIdx.x * 64;
  const int lrow = tid >> 2;          // 0..63 : tile row to load
  const int lk = (tid & 3) * 4;       // 0,4,8,12 : k offset (float4)
  const int am = m0 + lrow;
  const long abase = ((long)(am & 1) * T_ + (am >> 1)) * E_ + lk;
  const long bbase = (long)(n0 + lrow) * E_ + lk;

  float acc[4][4] = {};

  for (int k0 = 0; k0 < E_; k0 += 16) {
    const float4 av4 = *(const float4*)(X + abase + k0);
    const float4 bv4 = *(const float4*)(W + bbase + k0);
    __syncthreads();
    As[(lk + 0) * 68 + lrow] = av4.x;
    As[(lk + 1) * 68 + lrow] = av4.y;
    As[(lk + 2) * 68 + lrow] = av4.z;
    As[(lk + 3) * 68 + lrow] = av4.w;
    Bs[(lk + 0) * 68 + lrow] = bv4.x;
    Bs[(lk + 1) * 68 + lrow] = bv4.y;
    Bs[(lk + 2) * 68 + lrow] = bv4.z;
    Bs[(lk + 3) * 68 + lrow] = bv4.w;
    __syncthreads();
#pragma unroll
    for (int kk = 0; kk < 16; kk++) {
      const float4 a = *(const float4*)&As[kk * 68 + ty * 4];
      const float4 b = *(const float4*)&Bs[kk * 68 + tx * 4];
      const float avr[4] = {a.x, a.y, a.z, a.w};
      const float bvr[4] = {b.x, b.y, b.z, b.w};
#pragma unroll
      for (int i = 0; i < 4; i++)
#pragma unroll
        for (int j = 0; j < 4; j++) acc[i][j] += avr[i] * bvr[j];
    }
  }

#pragma unroll
  for (int i = 0; i < 4; i++) {
    const int mm = m0 + ty * 4 + i;
    float4 o;
    o.x = acc[i][0] + bias[n0 + tx * 4 + 0];
    o.y = acc[i][1] + bias[n0 + tx * 4 + 1];
    o.z = acc[i][2] + bias[n0 + tx * 4 + 2];
    o.w = acc[i][3] + bias[n0 + tx * 4 + 3];
    *(float4*)(C + (long)mm * E_ + n0 + tx * 4) = o;
  }
}

// ---------------------------------------------------------------------------
// Output projection: out[perm(p), n] = sum_k A[p,k]*W[n,k] + b[n]
// perm(p) = (p%T)*2 + p/T.
// ---------------------------------------------------------------------------
__global__ __launch_bounds__(256) void out_gemm(
    const float* __restrict__ A, const float* __restrict__ W,
    const float* __restrict__ bias, float* __restrict__ C)
{
  __shared__ __align__(16) float As[16 * 68];
  __shared__ __align__(16) float Bs[16 * 68];

  const int tid = threadIdx.x;
  const int tx = tid & 15, ty = tid >> 4;
  const int m0 = blockIdx.y * 64, n0 = blockIdx.x * 64;
  const int lrow = tid >> 2;
  const int lk = (tid & 3) * 4;
  const long abase = (long)(m0 + lrow) * E_ + lk;
  const long bbase = (long)(n0 + lrow) * E_ + lk;

  float acc[4][4] = {};

  for (int k0 = 0; k0 < E_; k0 += 16) {
    const float4 av4 = *(const float4*)(A + abase + k0);
    const float4 bv4 = *(const float4*)(W + bbase + k0);
    __syncthreads();
    As[(lk + 0) * 68 + lrow] = av4.x;
    As[(lk + 1) * 68 + lrow] = av4.y;
    As[(lk + 2) * 68 + lrow] = av4.z;
    As[(lk + 3) * 68 + lrow] = av4.w;
    Bs[(lk + 0) * 68 + lrow] = bv4.x;
    Bs[(lk + 1) * 68 + lrow] = bv4.y;
    Bs[(lk + 2) * 68 + lrow] = bv4.z;
    Bs[(lk + 3) * 68 + lrow] = bv4.w;
    __syncthreads();
#pragma unroll
    for (int kk = 0; kk < 16; kk++) {
      const float4 a = *(const float4*)&As[kk * 68 + ty * 4];
      const float4 b = *(const float4*)&Bs[kk * 68 + tx * 4];
      const float avr[4] = {a.x, a.y, a.z, a.w};
      const float bvr[4] = {b.x, b.y, b.z, b.w};
#pragma unroll
      for (int i = 0; i < 4; i++)
#pragma unroll
        for (int j = 0; j < 4; j++) acc[i][j] += avr[i] * bvr[j];
    }
  }

#pragma unroll
  for (int i = 0; i < 4; i++) {
    const int mm = m0 + ty * 4 + i;
    const int crow = (mm & (T_ - 1)) * B_ + (mm >> 11);  // t'*2 + b'
    float4 o;
    o.x = acc[i][0] + bias[n0 + tx * 4 + 0];
    o.y = acc[i][1] + bias[n0 + tx * 4 + 1];
    o.z = acc[i][2] + bias[n0 + tx * 4 + 2];
    o.w = acc[i][3] + bias[n0 + tx * 4 + 3];
    *(float4*)(C + (long)crow * E_ + n0 + tx * 4) = o;
  }
}

// ---------------------------------------------------------------------------
// LSH hash, thread-per-row (unchanged from round 3 — now ~fast).
// ---------------------------------------------------------------------------
__global__ __launch_bounds__(128) void hash_kernel(
    const float* __restrict__ Q, const float* __restrict__ K,
    const float* __restrict__ lshW, const float* __restrict__ lshb,
    int* __restrict__ qh, int* __restrict__ kh)
{
  __shared__ __align__(16) float xs[128 * 68];
  const int tid = threadIdx.x;
  const int tau0 = blockIdx.x * 128;
  const int src = tau0 >> 16;          // uniform per block
  const int r = (tau0 >> 15) & 1;
  const int rowbase = tau0 & 32767;
  const float* X = src ? K : Q;
  int* outh = src ? kh : qh;

  const float4* g = (const float4*)(X + (long)rowbase * 64);
#pragma unroll
  for (int it = 0; it < 16; it++) {
    const int gidx = it * 128 + tid;
    const int row = gidx >> 4, c4 = gidx & 15;
    *(float4*)&xs[row * 68 + c4 * 4] = g[gidx];
  }
  __syncthreads();

  float4 x[16];
#pragma unroll
  for (int i = 0; i < 16; i++) x[i] = *(const float4*)&xs[tid * 68 + i * 4];

  const float4* w4 = (const float4*)(lshW + (long)r * DH_ * DH_);
  const float* bb = lshb + r * DH_;

  float best = -INFINITY; int bi = 0;
  for (int j = 0; j < 64; j++) {
    float s = bb[j];
#pragma unroll
    for (int d = 0; d < 16; d++) {
      const float4 w = w4[j * 16 + d];       // wave-uniform -> s_load
      s += x[d].x * w.x + x[d].y * w.y + x[d].z * w.z + x[d].w * w.w;
    }
    if (s > best) { best = s; bi = j; }
  }

  const int rowidx = rowbase + tid;
  const int p = rowidx >> 3, h = rowidx & 7;
  const int b = p >> 11, t = p & (T_ - 1);
  outh[((r * 16) + b * H_ + h) * T_ + t] = bi;
}

// ---------------------------------------------------------------------------
// Sparse bucket attention. One wave per (b', h, t'), lane = head dim d.
// Softmax without max-subtraction (scores bounded ~|q||k|/8 << 88, so exp
// cannot overflow; ratio identical to softmax). Keys extracted from the
// ballot 4 at a time: 4 independent shuffle-reduction chains pipeline on
// the LDS pipe instead of serializing. kh chunk for the next iteration is
// prefetched before processing the current ballot.
// ---------------------------------------------------------------------------
__global__ __launch_bounds__(256) void attn_kernel(
    const float* __restrict__ Q, const float* __restrict__ Km,
    const float* __restrict__ V,
    const int* __restrict__ qh, const int* __restrict__ kh,
    float* __restrict__ attn)   // [M_*E_] averaged over rounds
{
  const int wid = threadIdx.x >> 6, lane = threadIdx.x & 63;
  const int t = blockIdx.x * 4 + wid;
  const int ctx = blockIdx.y;          // b'*8 + h
  const int b = ctx >> 3, h = ctx & 7;
  const long p = (long)b * T_ + t;

  const float* kbase = Km + ((long)b * T_) * E_ + h * DH_ + lane;
  const float* vbase = V + ((long)b * T_) * E_ + h * DH_ + lane;
  const float qd = Q[p * E_ + h * DH_ + lane];

  float acc = 0.f;
#pragma unroll
  for (int r = 0; r < NROUND; r++) {
    const int bq = qh[(r * 16 + ctx) * T_ + t];
    if (bq >= NBUCKET) continue;     // never attended (hash >= bucket count)
    const int* khp = kh + (r * 16 + ctx) * T_;

    float l = 0.f, o = 0.f;
    int myk = khp[lane];             // prefetch chunk 0
    for (int s0 = 0; s0 < T_; s0 += 64) {
      const int nk = (s0 + 64 < T_) ? khp[s0 + 64 + lane] : 0;  // prefetch next
      unsigned long long ball = __ballot(myk == bq);
      myk = nk;
      while (ball) {
        // extract up to 4 matched key indices (wave-uniform scalars)
        const int i0 = __builtin_ctzll(ball); ball &= ball - 1;
        const bool k1v = ball != 0;
        const int i1 = k1v ? __builtin_ctzll(ball) : i0; if (k1v) ball &= ball - 1;
        const bool k2v = ball != 0;
        const int i2 = k2v ? __builtin_ctzll(ball) : i0; if (k2v) ball &= ball - 1;
        const bool k3v = ball != 0;
        const int i3 = k3v ? __builtin_ctzll(ball) : i0; if (k3v) ball &= ball - 1;

        const long f0 = (long)(s0 + i0) * E_, f1 = (long)(s0 + i1) * E_;
        const long f2 = (long)(s0 + i2) * E_, f3 = (long)(s0 + i3) * E_;
        // issue all 8 loads before any math
        const float ka = kbase[f0], kb2 = kbase[f1], kc = kbase[f2], kd = kbase[f3];
        const float va = vbase[f0], vb2 = vbase[f1], vc = vbase[f2], vd = vbase[f3];

        float d0 = qd * ka, d1 = qd * kb2, d2 = qd * kc, d3 = qd * kd;
#pragma unroll
        for (int off = 32; off; off >>= 1) {   // 4 independent chains, pipelined
          d0 += __shfl_xor(d0, off);
          d1 += __shfl_xor(d1, off);
          d2 += __shfl_xor(d2, off);
          d3 += __shfl_xor(d3, off);
        }
        const float p0 = __expf(d0 * 0.125f);
        const float p1 = k1v ? __expf(d1 * 0.125f) : 0.f;
        const float p2 = k2v ? __expf(d2 * 0.125f) : 0.f;
        const float p3 = k3v ? __expf(d3 * 0.125f) : 0.f;
        l += (p0 + p1) + (p2 + p3);
        o += p0 * va + p1 * vb2 + p2 * vc + p3 * vd;
      }
    }
    if (l > 0.f) acc += o / l;       // l >= 1 whenever any key matched
  }
  attn[p * E_ + h * DH_ + lane] = 0.5f * acc;
}

// ---------------------------------------------------------------------------
extern "C" void kernel_launch(void* const* d_in, const int* in_sizes, int n_in,
                              void* d_out, int out_size, void* d_ws, size_t ws_size,
                              hipStream_t stream) {
  const float* query = (const float*)d_in[0];
  const float* key   = (const float*)d_in[1];
  const float* value = (const float*)d_in[2];
  const float* Wq = (const float*)d_in[3];
  const float* bq = (const float*)d_in[4];
  const float* Wk = (const float*)d_in[5];
  const float* bk = (const float*)d_in[6];
  const float* Wv = (const float*)d_in[7];
  const float* bv = (const float*)d_in[8];
  const float* Wo = (const float*)d_in[9];
  const float* bo = (const float*)d_in[10];
  const float* lshW = (const float*)d_in[11];
  const float* lshb = (const float*)d_in[12];

  const size_t MSZ = (size_t)M_ * E_;
  float* Q    = (float*)d_ws;          //  8 MB
  float* K    = Q + MSZ;               //  8 MB
  float* V    = K + MSZ;               //  8 MB
  float* attn = V + MSZ;               //  8 MB (round-averaged)
  int* qh = (int*)(attn + MSZ);        //  256 KB [2][16][T_]
  int* kh = qh + NROUND * 16 * T_;     //  256 KB

  qkv_gemm<<<dim3(E_ / 64, M_ / 64, 3), 256, 0, stream>>>(
      query, key, value, Wq, bq, Wk, bk, Wv, bv, Q, K, V);
  hash_kernel<<<dim3(1024), 128, 0, stream>>>(   // 2 src * 2 rounds * 32768 rows / 128
      Q, K, lshW, lshb, qh, kh);
  attn_kernel<<<dim3(T_ / 4, 16), 256, 0, stream>>>(
      Q, K, V, qh, kh, attn);
  out_gemm<<<dim3(E_ / 64, M_ / 64, 1), 256, 0, stream>>>(
      attn, Wo, bo, (float*)d_out);
}

// Round 5
// 384.790 us; speedup vs baseline: 1.2321x; 1.2321x over previous
//
#include <hip/hip_runtime.h>
#include <stdint.h>
#include <math.h>

// ReformerAttention on MI355X — all fp32 I/O (per reference dtypes).
// B=2, T=2048, E=512, H=8, Dh=64, 2 hash rounds, buckets<32 attend.
// Projection row p (of the [T*B,E]-flattened swapaxes result) = logical
// (b'=p/T, t'=p%T); it gathers input row (b=p%2, t=p/2).
//
// Pipeline: qkv_gemm -> hash -> [memset cnt] hist -> scan -> scatter(klist)
//           -> attn_seg (dense per-bucket key segments) -> out_gemm

#define T_ 2048
#define E_ 512
#define H_ 8
#define DH_ 64
#define B_ 2
#define M_ 4096        // B_*T_
#define NROUND 2
#define NBUCKET 32
#define NSEG 32        // NROUND * 16 (r,ctx) segments

// ---------------------------------------------------------------------------
// QKV projection: C[p,n] = sum_k X[gather(p),k]*W[n,k] + bias[n]
// ---------------------------------------------------------------------------
__global__ __launch_bounds__(256) void qkv_gemm(
    const float* __restrict__ Xq, const float* __restrict__ Xk,
    const float* __restrict__ Xv,
    const float* __restrict__ Wq, const float* __restrict__ bq,
    const float* __restrict__ Wk, const float* __restrict__ bk,
    const float* __restrict__ Wv, const float* __restrict__ bv,
    float* __restrict__ Qo, float* __restrict__ Ko, float* __restrict__ Vo)
{
  const float* X; const float* W; const float* bias; float* C;
  if (blockIdx.z == 0)      { X = Xq; W = Wq; bias = bq; C = Qo; }
  else if (blockIdx.z == 1) { X = Xk; W = Wk; bias = bk; C = Ko; }
  else                      { X = Xv; W = Wv; bias = bv; C = Vo; }

  __shared__ __align__(16) float As[16 * 68];  // [k][m], stride 68 breaks pow2
  __shared__ __align__(16) float Bs[16 * 68];  // [k][n]

  const int tid = threadIdx.x;
  const int tx = tid & 15, ty = tid >> 4;
  const int m0 = blockIdx.y * 64, n0 = blockIdx.x * 64;
  const int lrow = tid >> 2;          // 0..63 : tile row to load
  const int lk = (tid & 3) * 4;       // 0,4,8,12 : k offset (float4)
  const int am = m0 + lrow;
  const long abase = ((long)(am & 1) * T_ + (am >> 1)) * E_ + lk;
  const long bbase = (long)(n0 + lrow) * E_ + lk;

  float acc[4][4] = {};

  for (int k0 = 0; k0 < E_; k0 += 16) {
    const float4 av4 = *(const float4*)(X + abase + k0);
    const float4 bv4 = *(const float4*)(W + bbase + k0);
    __syncthreads();
    As[(lk + 0) * 68 + lrow] = av4.x;
    As[(lk + 1) * 68 + lrow] = av4.y;
    As[(lk + 2) * 68 + lrow] = av4.z;
    As[(lk + 3) * 68 + lrow] = av4.w;
    Bs[(lk + 0) * 68 + lrow] = bv4.x;
    Bs[(lk + 1) * 68 + lrow] = bv4.y;
    Bs[(lk + 2) * 68 + lrow] = bv4.z;
    Bs[(lk + 3) * 68 + lrow] = bv4.w;
    __syncthreads();
#pragma unroll
    for (int kk = 0; kk < 16; kk++) {
      const float4 a = *(const float4*)&As[kk * 68 + ty * 4];
      const float4 b = *(const float4*)&Bs[kk * 68 + tx * 4];
      const float avr[4] = {a.x, a.y, a.z, a.w};
      const float bvr[4] = {b.x, b.y, b.z, b.w};
#pragma unroll
      for (int i = 0; i < 4; i++)
#pragma unroll
        for (int j = 0; j < 4; j++) acc[i][j] += avr[i] * bvr[j];
    }
  }

#pragma unroll
  for (int i = 0; i < 4; i++) {
    const int mm = m0 + ty * 4 + i;
    float4 o;
    o.x = acc[i][0] + bias[n0 + tx * 4 + 0];
    o.y = acc[i][1] + bias[n0 + tx * 4 + 1];
    o.z = acc[i][2] + bias[n0 + tx * 4 + 2];
    o.w = acc[i][3] + bias[n0 + tx * 4 + 3];
    *(float4*)(C + (long)mm * E_ + n0 + tx * 4) = o;
  }
}

// ---------------------------------------------------------------------------
// Output projection: out[perm(p), n] = sum_k A[p,k]*W[n,k] + b[n]
// perm(p) = (p%T)*2 + p/T.
// ---------------------------------------------------------------------------
__global__ __launch_bounds__(256) void out_gemm(
    const float* __restrict__ A, const float* __restrict__ W,
    const float* __restrict__ bias, float* __restrict__ C)
{
  __shared__ __align__(16) float As[16 * 68];
  __shared__ __align__(16) float Bs[16 * 68];

  const int tid = threadIdx.x;
  const int tx = tid & 15, ty = tid >> 4;
  const int m0 = blockIdx.y * 64, n0 = blockIdx.x * 64;
  const int lrow = tid >> 2;
  const int lk = (tid & 3) * 4;
  const long abase = (long)(m0 + lrow) * E_ + lk;
  const long bbase = (long)(n0 + lrow) * E_ + lk;

  float acc[4][4] = {};

  for (int k0 = 0; k0 < E_; k0 += 16) {
    const float4 av4 = *(const float4*)(A + abase + k0);
    const float4 bv4 = *(const float4*)(W + bbase + k0);
    __syncthreads();
    As[(lk + 0) * 68 + lrow] = av4.x;
    As[(lk + 1) * 68 + lrow] = av4.y;
    As[(lk + 2) * 68 + lrow] = av4.z;
    As[(lk + 3) * 68 + lrow] = av4.w;
    Bs[(lk + 0) * 68 + lrow] = bv4.x;
    Bs[(lk + 1) * 68 + lrow] = bv4.y;
    Bs[(lk + 2) * 68 + lrow] = bv4.z;
    Bs[(lk + 3) * 68 + lrow] = bv4.w;
    __syncthreads();
#pragma unroll
    for (int kk = 0; kk < 16; kk++) {
      const float4 a = *(const float4*)&As[kk * 68 + ty * 4];
      const float4 b = *(const float4*)&Bs[kk * 68 + tx * 4];
      const float avr[4] = {a.x, a.y, a.z, a.w};
      const float bvr[4] = {b.x, b.y, b.z, b.w};
#pragma unroll
      for (int i = 0; i < 4; i++)
#pragma unroll
        for (int j = 0; j < 4; j++) acc[i][j] += avr[i] * bvr[j];
    }
  }

#pragma unroll
  for (int i = 0; i < 4; i++) {
    const int mm = m0 + ty * 4 + i;
    const int crow = (mm & (T_ - 1)) * B_ + (mm >> 11);  // t'*2 + b'
    float4 o;
    o.x = acc[i][0] + bias[n0 + tx * 4 + 0];
    o.y = acc[i][1] + bias[n0 + tx * 4 + 1];
    o.z = acc[i][2] + bias[n0 + tx * 4 + 2];
    o.w = acc[i][3] + bias[n0 + tx * 4 + 3];
    *(float4*)(C + (long)crow * E_ + n0 + tx * 4) = o;
  }
}

// ---------------------------------------------------------------------------
// LSH hash, thread-per-row (unchanged — ~15 µs).
// ---------------------------------------------------------------------------
__global__ __launch_bounds__(128) void hash_kernel(
    const float* __restrict__ Q, const float* __restrict__ K,
    const float* __restrict__ lshW, const float* __restrict__ lshb,
    int* __restrict__ qh, int* __restrict__ kh)
{
  __shared__ __align__(16) float xs[128 * 68];
  const int tid = threadIdx.x;
  const int tau0 = blockIdx.x * 128;
  const int src = tau0 >> 16;          // uniform per block
  const int r = (tau0 >> 15) & 1;
  const int rowbase = tau0 & 32767;
  const float* X = src ? K : Q;
  int* outh = src ? kh : qh;

  const float4* g = (const float4*)(X + (long)rowbase * 64);
#pragma unroll
  for (int it = 0; it < 16; it++) {
    const int gidx = it * 128 + tid;
    const int row = gidx >> 4, c4 = gidx & 15;
    *(float4*)&xs[row * 68 + c4 * 4] = g[gidx];
  }
  __syncthreads();

  float4 x[16];
#pragma unroll
  for (int i = 0; i < 16; i++) x[i] = *(const float4*)&xs[tid * 68 + i * 4];

  const float4* w4 = (const float4*)(lshW + (long)r * DH_ * DH_);
  const float* bb = lshb + r * DH_;

  float best = -INFINITY; int bi = 0;
  for (int j = 0; j < 64; j++) {
    float s = bb[j];
#pragma unroll
    for (int d = 0; d < 16; d++) {
      const float4 w = w4[j * 16 + d];       // wave-uniform -> s_load
      s += x[d].x * w.x + x[d].y * w.y + x[d].z * w.z + x[d].w * w.w;
    }
    if (s > best) { best = s; bi = j; }
  }

  const int rowidx = rowbase + tid;
  const int p = rowidx >> 3, h = rowidx & 7;
  const int b = p >> 11, t = p & (T_ - 1);
  outh[((r * 16) + b * H_ + h) * T_ + t] = bi;
}

// ---------------------------------------------------------------------------
// Key bucket sort: histogram -> exclusive scan -> scatter.
// seg = r*16 + ctx (32 segments of 2048 keys each). Only kh<32 is attendable.
// ---------------------------------------------------------------------------
__global__ __launch_bounds__(256) void hist_kernel(
    const int* __restrict__ kh, int* __restrict__ kcnt)
{
  const int idx = blockIdx.x * 256 + threadIdx.x;    // < NSEG*T_
  const int v = kh[idx];
  if (v < NBUCKET) atomicAdd(&kcnt[(idx >> 11) * NBUCKET + v], 1);
}

__global__ void scan_kernel(const int* __restrict__ kcnt,
                            int* __restrict__ koff, int* __restrict__ kcur)
{
  const int seg = threadIdx.x;
  if (seg >= NSEG) return;
  int run = 0;
  for (int b = 0; b < NBUCKET; b++) {
    koff[seg * (NBUCKET + 1) + b] = run;
    kcur[seg * NBUCKET + b] = run;
    run += kcnt[seg * NBUCKET + b];
  }
  koff[seg * (NBUCKET + 1) + NBUCKET] = run;
}

__global__ __launch_bounds__(256) void scatter_kernel(
    const int* __restrict__ kh, int* __restrict__ kcur,
    int* __restrict__ klist)
{
  const int idx = blockIdx.x * 256 + threadIdx.x;
  const int v = kh[idx];
  if (v < NBUCKET) {
    const int seg = idx >> 11;
    const int pos = atomicAdd(&kcur[seg * NBUCKET + v], 1);
    klist[seg * T_ + pos] = idx & (T_ - 1);          // key's t index in ctx
  }
}

// ---------------------------------------------------------------------------
// Sparse bucket attention over sorted key segments. One wave per (b',h,t'),
// lane = head dim d. Query walks its bucket's dense key list 4 at a time:
// 4 independent shuffle-reduce chains pipeline. No-max softmax (scores
// bounded |q||k|/8 << 88; ratio identical to softmax).
// ---------------------------------------------------------------------------
__global__ __launch_bounds__(256) void attn_seg(
    const float* __restrict__ Q, const float* __restrict__ Km,
    const float* __restrict__ V,
    const int* __restrict__ qh, const int* __restrict__ klist,
    const int* __restrict__ koff,
    float* __restrict__ attn)   // [M_*E_] averaged over rounds
{
  const int wid = threadIdx.x >> 6, lane = threadIdx.x & 63;
  const int t = blockIdx.x * 4 + wid;
  const int ctx = blockIdx.y;          // b'*8 + h
  const int b = ctx >> 3, h = ctx & 7;
  const long p = (long)b * T_ + t;

  const float* kbase = Km + ((long)b * T_) * E_ + h * DH_ + lane;
  const float* vbase = V + ((long)b * T_) * E_ + h * DH_ + lane;
  const float qd = Q[p * E_ + h * DH_ + lane];

  float acc = 0.f;
#pragma unroll
  for (int r = 0; r < NROUND; r++) {
    const int seg = r * 16 + ctx;
    const int bq = qh[seg * T_ + t];
    if (bq >= NBUCKET) continue;     // never attended (hash >= bucket count)
    const int lo = koff[seg * (NBUCKET + 1) + bq];
    const int hi = koff[seg * (NBUCKET + 1) + bq + 1];
    const int* kl = klist + seg * T_;

    float l = 0.f, o = 0.f;
    for (int j = lo; j < hi; j += 4) {
      const int s0 = kl[j];
      const bool k1v = j + 1 < hi, k2v = j + 2 < hi, k3v = j + 3 < hi;
      const int s1 = k1v ? kl[j + 1] : s0;
      const int s2 = k2v ? kl[j + 2] : s0;
      const int s3 = k3v ? kl[j + 3] : s0;

      const long f0 = (long)s0 * E_, f1 = (long)s1 * E_;
      const long f2 = (long)s2 * E_, f3 = (long)s3 * E_;
      // issue all 8 row loads before any math (coalesced, lane = d)
      const float ka = kbase[f0], kb2 = kbase[f1], kc = kbase[f2], kd = kbase[f3];
      const float va = vbase[f0], vb2 = vbase[f1], vc = vbase[f2], vd = vbase[f3];

      float d0 = qd * ka, d1 = qd * kb2, d2 = qd * kc, d3 = qd * kd;
#pragma unroll
      for (int off = 32; off; off >>= 1) {   // 4 independent chains, pipelined
        d0 += __shfl_xor(d0, off);
        d1 += __shfl_xor(d1, off);
        d2 += __shfl_xor(d2, off);
        d3 += __shfl_xor(d3, off);
      }
      const float p0 = __expf(d0 * 0.125f);
      const float p1 = k1v ? __expf(d1 * 0.125f) : 0.f;
      const float p2 = k2v ? __expf(d2 * 0.125f) : 0.f;
      const float p3 = k3v ? __expf(d3 * 0.125f) : 0.f;
      l += (p0 + p1) + (p2 + p3);
      o += p0 * va + p1 * vb2 + p2 * vc + p3 * vd;
    }
    if (l > 0.f) acc += o / l;       // segment empty -> l==0 -> no contribution
  }
  attn[p * E_ + h * DH_ + lane] = 0.5f * acc;
}

// ---------------------------------------------------------------------------
extern "C" void kernel_launch(void* const* d_in, const int* in_sizes, int n_in,
                              void* d_out, int out_size, void* d_ws, size_t ws_size,
                              hipStream_t stream) {
  const float* query = (const float*)d_in[0];
  const float* key   = (const float*)d_in[1];
  const float* value = (const float*)d_in[2];
  const float* Wq = (const float*)d_in[3];
  const float* bq = (const float*)d_in[4];
  const float* Wk = (const float*)d_in[5];
  const float* bk = (const float*)d_in[6];
  const float* Wv = (const float*)d_in[7];
  const float* bv = (const float*)d_in[8];
  const float* Wo = (const float*)d_in[9];
  const float* bo = (const float*)d_in[10];
  const float* lshW = (const float*)d_in[11];
  const float* lshb = (const float*)d_in[12];

  const size_t MSZ = (size_t)M_ * E_;
  float* Q    = (float*)d_ws;            //  8 MB
  float* K    = Q + MSZ;                 //  8 MB
  float* V    = K + MSZ;                 //  8 MB
  float* attn = V + MSZ;                 //  8 MB (round-averaged)
  int* qh    = (int*)(attn + MSZ);       // [NSEG][T_]  256 KB
  int* kh    = qh + NSEG * T_;           // [NSEG][T_]  256 KB
  int* klist = kh + NSEG * T_;           // [NSEG][T_]  256 KB
  int* kcnt  = klist + NSEG * T_;        // [NSEG][32]
  int* kcur  = kcnt + NSEG * NBUCKET;    // [NSEG][32]
  int* koff  = kcur + NSEG * NBUCKET;    // [NSEG][33]

  qkv_gemm<<<dim3(E_ / 64, M_ / 64, 3), 256, 0, stream>>>(
      query, key, value, Wq, bq, Wk, bk, Wv, bv, Q, K, V);
  hash_kernel<<<dim3(1024), 128, 0, stream>>>(
      Q, K, lshW, lshb, qh, kh);
  hipMemsetAsync(kcnt, 0, NSEG * NBUCKET * sizeof(int), stream);
  hist_kernel<<<dim3(NSEG * T_ / 256), 256, 0, stream>>>(kh, kcnt);
  scan_kernel<<<dim3(1), 64, 0, stream>>>(kcnt, koff, kcur);
  scatter_kernel<<<dim3(NSEG * T_ / 256), 256, 0, stream>>>(kh, kcur, klist);
  attn_seg<<<dim3(T_ / 4, 16), 256, 0, stream>>>(
      Q, K, V, qh, klist, koff, attn);
  out_gemm<<<dim3(E_ / 64, M_ / 64, 1), 256, 0, stream>>>(
      attn, Wo, bo, (float*)d_out);
}